// Round 3
// baseline (419.685 us; speedup 1.0000x reference)
//
#include <hip/hip_runtime.h>

#define IH 512
#define IW 512
#define OH 502
#define OW 502
#define KS 11
#define TILE 32
#define IN_TP 44               /* padded v-array row: 11 chunks of 4 floats */
#define NCH 48                 /* 16*3 */
#define TPD 16                 /* ceil(502/32) tiles per dim */
#define NBLK (NCH * TPD * TPD)
#define C1f 0.0001f
#define C2f 0.0009f

// Gaussian(sigma=1.5, k=11) weights, precomputed in double precision.
__device__ __constant__ float g_w[KS] = {
    0.00102838f, 0.00759876f, 0.03600077f, 0.10936069f, 0.21300554f,
    0.26601173f, 0.21300554f, 0.10936069f, 0.03600077f, 0.00759876f,
    0.00102838f};

__global__ __launch_bounds__(256) void ssim_main(const float* __restrict__ x,
                                                 const float* __restrict__ y,
                                                 double* __restrict__ acc,
                                                 unsigned int* __restrict__ cnt,
                                                 float* __restrict__ out) {
    __shared__ float v0[TILE][IN_TP];
    __shared__ float v1[TILE][IN_TP];
    __shared__ float v2[TILE][IN_TP];
    __shared__ float v3[TILE][IN_TP];
    __shared__ float v4[TILE][IN_TP];
    __shared__ float red[4];

    const int bid = blockIdx.x;
    const int ch = bid / (TPD * TPD);
    const int tile = bid % (TPD * TPD);
    const int ti = tile / TPD, tj = tile % TPD;
    const int row0 = ti * TILE, col0 = tj * TILE;
    const float* __restrict__ xc = x + (size_t)ch * IH * IW;
    const float* __restrict__ yc = y + (size_t)ch * IH * IW;
    const int tid = threadIdx.x;

    // ---- stage 1: vertical blur of 5 quantities, reading x/y directly from
    // global (L1/L2-resident tile region), writing 4-col chunks to LDS ----
    // 32 rows * 11 chunks = 352 tasks
    for (int m = tid; m < TILE * 11; m += 256) {
        const int r = m / 11, c4 = (m % 11) * 4;
        const int gcb = col0 + c4;
        const bool interior = (gcb + 3 <= IW - 1);
        float s0[4] = {0.f, 0.f, 0.f, 0.f};
        float s1[4] = {0.f, 0.f, 0.f, 0.f};
        float s2[4] = {0.f, 0.f, 0.f, 0.f};
        float s3[4] = {0.f, 0.f, 0.f, 0.f};
        float s4[4] = {0.f, 0.f, 0.f, 0.f};
#pragma unroll
        for (int t = 0; t < KS; ++t) {
            const float w = g_w[t];
            const int gr = min(row0 + r + t, IH - 1);
            const float* xrow = xc + gr * IW;
            const float* yrow = yc + gr * IW;
            float xa[4], ya[4];
            if (interior) {
                const float4 xv = *(const float4*)(xrow + gcb);
                const float4 yv = *(const float4*)(yrow + gcb);
                xa[0] = xv.x; xa[1] = xv.y; xa[2] = xv.z; xa[3] = xv.w;
                ya[0] = yv.x; ya[1] = yv.y; ya[2] = yv.z; ya[3] = yv.w;
            } else {
#pragma unroll
                for (int j = 0; j < 4; ++j) {
                    const int gc = min(gcb + j, IW - 1);
                    xa[j] = xrow[gc];
                    ya[j] = yrow[gc];
                }
            }
#pragma unroll
            for (int j = 0; j < 4; ++j) {
                const float wx = w * xa[j];
                const float wy = w * ya[j];
                s0[j] += wx;
                s1[j] += wy;
                s2[j] = fmaf(wx, xa[j], s2[j]);
                s3[j] = fmaf(wy, ya[j], s3[j]);
                s4[j] = fmaf(wx, ya[j], s4[j]);
            }
        }
        *(float4*)&v0[r][c4] = make_float4(s0[0], s0[1], s0[2], s0[3]);
        *(float4*)&v1[r][c4] = make_float4(s1[0], s1[1], s1[2], s1[3]);
        *(float4*)&v2[r][c4] = make_float4(s2[0], s2[1], s2[2], s2[3]);
        *(float4*)&v3[r][c4] = make_float4(s3[0], s3[1], s3[2], s3[3]);
        *(float4*)&v4[r][c4] = make_float4(s4[0], s4[1], s4[2], s4[3]);
    }
    __syncthreads();

    // ---- stage 2: horizontal blur + ssim, one 1x4 output chunk per thread ----
    float lsum = 0.f;
    {
        const int r = tid >> 3;          // 32 rows
        const int c4 = (tid & 7) * 4;    // 8 chunks of 4 output cols
        const int gr = row0 + r;

        float m0[4], m1[4], m2[4], m3[4], m4[4];

#define HBLUR(VARR, OUT)                                                    \
        {                                                                   \
            float f[16];                                                    \
            *(float4*)&f[0]  = *(const float4*)&VARR[r][c4];                \
            *(float4*)&f[4]  = *(const float4*)&VARR[r][c4 + 4];            \
            *(float4*)&f[8]  = *(const float4*)&VARR[r][c4 + 8];            \
            *(float4*)&f[12] = *(const float4*)&VARR[r][c4 + 12];           \
            _Pragma("unroll")                                               \
            for (int cc = 0; cc < 4; ++cc) {                                \
                float s = 0.f;                                              \
                _Pragma("unroll")                                           \
                for (int t = 0; t < KS; ++t) s = fmaf(g_w[t], f[cc + t], s);\
                OUT[cc] = s;                                                \
            }                                                               \
        }

        HBLUR(v0, m0)
        HBLUR(v1, m1)
        HBLUR(v2, m2)
        HBLUR(v3, m3)
        HBLUR(v4, m4)
#undef HBLUR

        if (gr < OH) {
#pragma unroll
            for (int cc = 0; cc < 4; ++cc) {
                const int gc = col0 + c4 + cc;
                if (gc < OW) {
                    const float mux2 = m0[cc] * m0[cc];
                    const float muy2 = m1[cc] * m1[cc];
                    const float muxy = m0[cc] * m1[cc];
                    const float vx = m2[cc] - mux2;
                    const float vy = m3[cc] - muy2;
                    const float cxy = m4[cc] - muxy;
                    const float num = (2.f * muxy + C1f) * (2.f * cxy + C2f);
                    const float den = (mux2 + muy2 + C1f) * (vx + vy + C2f);
                    lsum += num / den;
                }
            }
        }
    }

    // ---- block reduce (4 waves of 64) + last-block finalize ----
#pragma unroll
    for (int off = 32; off > 0; off >>= 1) lsum += __shfl_down(lsum, off, 64);
    const int wave = tid >> 6, lane = tid & 63;
    if (lane == 0) red[wave] = lsum;
    __syncthreads();
    if (tid == 0) {
        const float bs = red[0] + red[1] + red[2] + red[3];
        atomicAdd(acc, (double)bs);
        __threadfence();
        const unsigned int prev = atomicAdd(cnt, 1u);
        if (prev == (unsigned int)(NBLK - 1)) {
            const double total = atomicAdd(acc, 0.0);  // L2-coherent read
            out[0] = (float)(1.0 - total / 12096192.0);  // 48*502*502
        }
    }
}

extern "C" void kernel_launch(void* const* d_in, const int* in_sizes, int n_in,
                              void* d_out, int out_size, void* d_ws, size_t ws_size,
                              hipStream_t stream) {
    const float* x = (const float*)d_in[0];
    const float* y = (const float*)d_in[1];
    float* out = (float*)d_out;
    double* acc = (double*)d_ws;
    unsigned int* cnt = (unsigned int*)((char*)d_ws + 8);

    hipMemsetAsync(d_ws, 0, 16, stream);
    ssim_main<<<NBLK, 256, 0, stream>>>(x, y, acc, cnt, out);
}

// Round 4
// 113.346 us; speedup vs baseline: 3.7027x; 3.7027x over previous
//
#include <hip/hip_runtime.h>

#define IH 512
#define IW 512
#define OH 502
#define OW 502
#define KS 11
#define HO 16                 /* output rows per strip */
#define NSTRIP 32             /* ceil(502/16) */
#define NCH 48                /* 16*3 */
#define NBLK (NCH * NSTRIP)   /* 1536 */
#define NT 128                /* threads: 128 chunks * 4 cols = 512 cols */
#define LROW 528              /* padded LDS row length in floats */
#define C1f 0.0001f
#define C2f 0.0009f

// Gaussian(sigma=1.5, k=11) weights, precomputed in double precision.
__device__ __constant__ float g_w[KS] = {
    0.00102838f, 0.00759876f, 0.03600077f, 0.10936069f, 0.21300554f,
    0.26601173f, 0.21300554f, 0.10936069f, 0.03600077f, 0.00759876f,
    0.00102838f};

__global__ __launch_bounds__(NT, 3) void ssim_main(const float* __restrict__ x,
                                                   const float* __restrict__ y,
                                                   double* __restrict__ acc,
                                                   unsigned int* __restrict__ cnt,
                                                   float* __restrict__ out) {
    __shared__ float lds[2][5][LROW];
    __shared__ float red[2];

    const int t = threadIdx.x;            // chunk id, cols 4t..4t+3
    const int ch = blockIdx.x / NSTRIP;
    const int strip = blockIdx.x % NSTRIP;
    const int r0 = strip * HO;
    const float* __restrict__ xc = x + (size_t)ch * IH * IW + 4 * t;
    const float* __restrict__ yc = y + (size_t)ch * IH * IW + 4 * t;

    // ---- warmup: fill ring with input rows r0..r0+9 ----
    float4 rx[11], ry[11];
#pragma unroll
    for (int i = 0; i < 10; ++i) {
        const int gr = min(r0 + i, IH - 1);
        rx[i] = *(const float4*)(xc + gr * IW);
        ry[i] = *(const float4*)(yc + gr * IW);
    }
    float4 nx, ny;
    {
        const int gr = min(r0 + 10, IH - 1);
        nx = *(const float4*)(xc + gr * IW);
        ny = *(const float4*)(yc + gr * IW);
    }

    float lsum = 0.f;

#pragma unroll
    for (int k = 0; k < HO; ++k) {
        // commit prefetched row into ring slot (static index after unroll)
        const int slot = (10 + k) % 11;
        rx[slot] = nx;
        ry[slot] = ny;
        // prefetch next row (consumed next iteration; hides HBM latency
        // under this iteration's ~600 VALU ops)
        if (k < HO - 1) {
            const int gr = min(r0 + 11 + k, IH - 1);
            nx = *(const float4*)(xc + gr * IW);
            ny = *(const float4*)(yc + gr * IW);
        }

        // ---- vertical blur of 5 quantities from registers ----
        float s0[4] = {0.f, 0.f, 0.f, 0.f};
        float s1[4] = {0.f, 0.f, 0.f, 0.f};
        float s2[4] = {0.f, 0.f, 0.f, 0.f};
        float s3[4] = {0.f, 0.f, 0.f, 0.f};
        float s4[4] = {0.f, 0.f, 0.f, 0.f};
#pragma unroll
        for (int tp = 0; tp < KS; ++tp) {
            const int sl = (k + tp) % 11;   // static after unroll
            const float w = g_w[tp];
            const float xa[4] = {rx[sl].x, rx[sl].y, rx[sl].z, rx[sl].w};
            const float ya[4] = {ry[sl].x, ry[sl].y, ry[sl].z, ry[sl].w};
#pragma unroll
            for (int j = 0; j < 4; ++j) {
                const float wx = w * xa[j];
                const float wy = w * ya[j];
                s0[j] += wx;
                s1[j] += wy;
                s2[j] = fmaf(wx, xa[j], s2[j]);
                s3[j] = fmaf(wy, ya[j], s3[j]);
                s4[j] = fmaf(wx, ya[j], s4[j]);
            }
        }

        const int b = k & 1;
        *(float4*)&lds[b][0][4 * t] = make_float4(s0[0], s0[1], s0[2], s0[3]);
        *(float4*)&lds[b][1][4 * t] = make_float4(s1[0], s1[1], s1[2], s1[3]);
        *(float4*)&lds[b][2][4 * t] = make_float4(s2[0], s2[1], s2[2], s2[3]);
        *(float4*)&lds[b][3][4 * t] = make_float4(s3[0], s3[1], s3[2], s3[3]);
        *(float4*)&lds[b][4][4 * t] = make_float4(s4[0], s4[1], s4[2], s4[3]);
        __syncthreads();

        // ---- horizontal blur + ssim for output row r0+k, cols 4t..4t+3 ----
        const int orow = r0 + k;
        float m[5][4];
#pragma unroll
        for (int q = 0; q < 5; ++q) {
            float f[16];
#pragma unroll
            for (int a = 0; a < 4; ++a)
                *(float4*)&f[4 * a] = *(const float4*)&lds[b][q][4 * t + 4 * a];
#pragma unroll
            for (int cc = 0; cc < 4; ++cc) {
                float s = 0.f;
#pragma unroll
                for (int tp = 0; tp < KS; ++tp) s = fmaf(g_w[tp], f[cc + tp], s);
                m[q][cc] = s;
            }
        }
        if (orow < OH) {
#pragma unroll
            for (int cc = 0; cc < 4; ++cc) {
                const int gc = 4 * t + cc;
                if (gc < OW) {
                    const float mux2 = m[0][cc] * m[0][cc];
                    const float muy2 = m[1][cc] * m[1][cc];
                    const float muxy = m[0][cc] * m[1][cc];
                    const float vx = m[2][cc] - mux2;
                    const float vy = m[3][cc] - muy2;
                    const float cxy = m[4][cc] - muxy;
                    const float num = (2.f * muxy + C1f) * (2.f * cxy + C2f);
                    const float den = (mux2 + muy2 + C1f) * (vx + vy + C2f);
                    lsum += num / den;
                }
            }
        }
    }

    // ---- block reduce (2 waves of 64) + last-block finalize ----
#pragma unroll
    for (int off = 32; off > 0; off >>= 1) lsum += __shfl_down(lsum, off, 64);
    const int wave = t >> 6, lane = t & 63;
    if (lane == 0) red[wave] = lsum;
    __syncthreads();
    if (t == 0) {
        const float bs = red[0] + red[1];
        atomicAdd(acc, (double)bs);
        __threadfence();
        const unsigned int prev = atomicAdd(cnt, 1u);
        if (prev == (unsigned int)(NBLK - 1)) {
            const double total = atomicAdd(acc, 0.0);  // coherent read
            out[0] = (float)(1.0 - total / 12096192.0);  // 48*502*502
        }
    }
}

extern "C" void kernel_launch(void* const* d_in, const int* in_sizes, int n_in,
                              void* d_out, int out_size, void* d_ws, size_t ws_size,
                              hipStream_t stream) {
    const float* x = (const float*)d_in[0];
    const float* y = (const float*)d_in[1];
    float* out = (float*)d_out;
    double* acc = (double*)d_ws;
    unsigned int* cnt = (unsigned int*)((char*)d_ws + 8);

    hipMemsetAsync(d_ws, 0, 16, stream);
    ssim_main<<<NBLK, NT, 0, stream>>>(x, y, acc, cnt, out);
}

// Round 5
// 96.916 us; speedup vs baseline: 4.3304x; 1.1695x over previous
//
#include <hip/hip_runtime.h>

#define IH 512
#define IW 512
#define OH 502
#define OW 502
#define KS 11
#define HO 16                 /* output rows per strip */
#define NSTRIP 32             /* ceil(502/16) */
#define NCH 48                /* 16*3 */
#define NBLK (NCH * NSTRIP)   /* 1536 */
#define NT 128                /* threads: 128 chunks * 4 cols = 512 cols */
#define LROW 528              /* padded LDS row length in floats */
#define C1f 0.0001f
#define C2f 0.0009f

// Gaussian(sigma=1.5, k=11) weights, precomputed in double precision.
__device__ __constant__ float g_w[KS] = {
    0.00102838f, 0.00759876f, 0.03600077f, 0.10936069f, 0.21300554f,
    0.26601173f, 0.21300554f, 0.10936069f, 0.03600077f, 0.00759876f,
    0.00102838f};

__global__ __launch_bounds__(NT, 3) void ssim_main(const float* __restrict__ x,
                                                   const float* __restrict__ y,
                                                   double* __restrict__ acc,
                                                   unsigned int* __restrict__ cnt,
                                                   float* __restrict__ out) {
    __shared__ float lds[2][5][LROW];
    __shared__ float red[2];

    const int t = threadIdx.x;            // chunk id, cols 4t..4t+3
    const int ch = blockIdx.x / NSTRIP;
    const int strip = blockIdx.x % NSTRIP;
    const int r0 = strip * HO;
    const float* __restrict__ xc = x + (size_t)ch * IH * IW + 4 * t;
    const float* __restrict__ yc = y + (size_t)ch * IH * IW + 4 * t;

    // ---- warmup: ring holds input rows r0 .. r0+10 (all indices static) ----
    float4 rx[KS], ry[KS];
#pragma unroll
    for (int i = 0; i < KS; ++i) {
        const int gr = min(r0 + i, IH - 1);
        rx[i] = *(const float4*)(xc + gr * IW);
        ry[i] = *(const float4*)(yc + gr * IW);
    }
    // prefetch row r0+11 (inserted at end of iter 0)
    float4 nx, ny;
    {
        const int gr = min(r0 + KS, IH - 1);
        nx = *(const float4*)(xc + gr * IW);
        ny = *(const float4*)(yc + gr * IW);
    }

    float lsum = 0.f;

#pragma unroll 2
    for (int k = 0; k < HO; ++k) {
        // ---- vertical blur of 5 quantities from the register ring ----
        float s0[4] = {0.f, 0.f, 0.f, 0.f};
        float s1[4] = {0.f, 0.f, 0.f, 0.f};
        float s2[4] = {0.f, 0.f, 0.f, 0.f};
        float s3[4] = {0.f, 0.f, 0.f, 0.f};
        float s4[4] = {0.f, 0.f, 0.f, 0.f};
#pragma unroll
        for (int tp = 0; tp < KS; ++tp) {
            const float w = g_w[tp];
            const float xa[4] = {rx[tp].x, rx[tp].y, rx[tp].z, rx[tp].w};
            const float ya[4] = {ry[tp].x, ry[tp].y, ry[tp].z, ry[tp].w};
#pragma unroll
            for (int j = 0; j < 4; ++j) {
                const float wx = w * xa[j];
                const float wy = w * ya[j];
                s0[j] += wx;
                s1[j] += wy;
                s2[j] = fmaf(wx, xa[j], s2[j]);
                s3[j] = fmaf(wy, ya[j], s3[j]);
                s4[j] = fmaf(wx, ya[j], s4[j]);
            }
        }

        const int b = k & 1;   // compile-time under unroll 2
        *(float4*)&lds[b][0][4 * t] = make_float4(s0[0], s0[1], s0[2], s0[3]);
        *(float4*)&lds[b][1][4 * t] = make_float4(s1[0], s1[1], s1[2], s1[3]);
        *(float4*)&lds[b][2][4 * t] = make_float4(s2[0], s2[1], s2[2], s2[3]);
        *(float4*)&lds[b][3][4 * t] = make_float4(s3[0], s3[1], s3[2], s3[3]);
        *(float4*)&lds[b][4][4 * t] = make_float4(s4[0], s4[1], s4[2], s4[3]);
        __syncthreads();   // also drains last iter's prefetch (issued ~full blur ago)

        // ---- horizontal blur + ssim for output row r0+k, cols 4t..4t+3 ----
        const int orow = r0 + k;
        float m[5][4];
#pragma unroll
        for (int q = 0; q < 5; ++q) {
            float f[16];
#pragma unroll
            for (int a = 0; a < 4; ++a)
                *(float4*)&f[4 * a] = *(const float4*)&lds[b][q][4 * t + 4 * a];
#pragma unroll
            for (int cc = 0; cc < 4; ++cc) {
                float s = 0.f;
#pragma unroll
                for (int tp = 0; tp < KS; ++tp) s = fmaf(g_w[tp], f[cc + tp], s);
                m[q][cc] = s;
            }
        }
        if (orow < OH) {
#pragma unroll
            for (int cc = 0; cc < 4; ++cc) {
                const int gc = 4 * t + cc;
                if (gc < OW) {
                    const float mux2 = m[0][cc] * m[0][cc];
                    const float muy2 = m[1][cc] * m[1][cc];
                    const float muxy = m[0][cc] * m[1][cc];
                    const float vx = m[2][cc] - mux2;
                    const float vy = m[3][cc] - muy2;
                    const float cxy = m[4][cc] - muxy;
                    const float num = (2.f * muxy + C1f) * (2.f * cxy + C2f);
                    const float den = (mux2 + muy2 + C1f) * (vx + vy + C2f);
                    // rcp + 1 Newton step instead of IEEE divide
                    float r = __builtin_amdgcn_rcpf(den);
                    r = r * fmaf(-den, r, 2.0f);
                    lsum = fmaf(num, r, lsum);
                }
            }
        }

        // ---- shift ring (static indices -> stays in VGPRs), insert prefetch ----
#pragma unroll
        for (int i = 0; i < KS - 1; ++i) { rx[i] = rx[i + 1]; ry[i] = ry[i + 1]; }
        rx[KS - 1] = nx;
        ry[KS - 1] = ny;

        // ---- issue next prefetch (consumed end of next iter) ----
        {
            const int gr = min(r0 + k + KS + 1, IH - 1);
            nx = *(const float4*)(xc + gr * IW);
            ny = *(const float4*)(yc + gr * IW);
        }
    }

    // ---- block reduce (2 waves of 64) + last-block finalize ----
#pragma unroll
    for (int off = 32; off > 0; off >>= 1) lsum += __shfl_down(lsum, off, 64);
    const int wave = t >> 6, lane = t & 63;
    if (lane == 0) red[wave] = lsum;
    __syncthreads();
    if (t == 0) {
        const float bs = red[0] + red[1];
        atomicAdd(acc, (double)bs);
        __threadfence();
        const unsigned int prev = atomicAdd(cnt, 1u);
        if (prev == (unsigned int)(NBLK - 1)) {
            const double total = atomicAdd(acc, 0.0);  // coherent read
            out[0] = (float)(1.0 - total / 12096192.0);  // 48*502*502
        }
    }
}

extern "C" void kernel_launch(void* const* d_in, const int* in_sizes, int n_in,
                              void* d_out, int out_size, void* d_ws, size_t ws_size,
                              hipStream_t stream) {
    const float* x = (const float*)d_in[0];
    const float* y = (const float*)d_in[1];
    float* out = (float*)d_out;
    double* acc = (double*)d_ws;
    unsigned int* cnt = (unsigned int*)((char*)d_ws + 8);

    hipMemsetAsync(d_ws, 0, 16, stream);
    ssim_main<<<NBLK, NT, 0, stream>>>(x, y, acc, cnt, out);
}